// Round 12
// baseline (87.004 us; speedup 1.0000x reference)
//
#include <hip/hip_runtime.h>

#define Hh 384
#define Ww 384
#define Bb 4
#define NN 64
#define HW (Hh*Ww)
#define NSEG (NN-1)
#define TPB 24                        // 24x24 tiles of 16x16
#define NTILES (TPB*TPB)              // 576 per batch

// ---------------- compile-time Ainv = (I + 0.1*A)^-1 (banded LU, f32) ------
struct AinvT { float a[NN][NN]; };
constexpr AinvT make_ainv() {
    AinvT R{};
    float d[NN] = {}, u1[NN] = {}, u2[NN] = {}, b1[NN] = {}, L1[NN] = {}, L2[NN] = {};
    for (int k = 0; k < NN-1; ++k) { d[k] += 0.01f; d[k+1] += 0.01f; u1[k] -= 0.01f; }
    for (int k = 0; k < NN-2; ++k) {
        d[k] += 0.01f; d[k+1] += 0.04f; d[k+2] += 0.01f;
        u1[k] -= 0.02f; u1[k+1] -= 0.02f; u2[k] += 0.01f;
    }
    for (int k = 0; k < NN; ++k) {
        d[k]  = 1.0f + 0.1f*d[k];
        u1[k] = 0.1f*u1[k];
        u2[k] = 0.1f*u2[k];
        b1[k] = u1[k];
    }
    for (int k = 0; k < NN; ++k) {
        float di = d[k];
        if (k+1 < NN) { float l = b1[k]/di; L1[k] = l; d[k+1] -= l*u1[k]; if (k+2 < NN) u1[k+1] -= l*u2[k]; }
        if (k+2 < NN) { float l = u2[k]/di; L2[k] = l; b1[k+1] -= l*u1[k]; d[k+2] -= l*u2[k]; }
    }
    for (int t = 0; t < NN; ++t) {
        float y[NN] = {}, x[NN] = {};
        for (int k = 0; k < NN; ++k) {
            float v = (k == t) ? 1.0f : 0.0f;
            if (k >= 1) v -= L1[k-1]*y[k-1];
            if (k >= 2) v -= L2[k-2]*y[k-2];
            y[k] = v;
        }
        for (int kk = 0; kk < NN; ++kk) {
            int k = NN-1-kk;
            float v = y[k];
            if (k+1 < NN) v -= u1[k]*x[k+1];
            if (k+2 < NN) v -= u2[k]*x[k+2];
            x[k] = v/d[k];
        }
        for (int k = 0; k < NN; ++k) R.a[k][t] = x[k];
    }
    return R;
}
__device__ constexpr AinvT g_Ainv = make_ainv();

// ------- snake: fused conv+bilinear grad, 20 steps + widths + prep ---------
// Bilinear(conv(pred,F))(x,y) == sum_{s,t in [0,18)} Wx[s]*Wy[t]*pred[x0+s-8,y0+t-8]
// with Wx[s] = (1-fx)*tap[s] + fx*tap[s-1] (zero outside [0,17)), zero-padded
// image reads. Channel0: Wx from dg, Wy from g. Channel1: Wx from g, Wy from dg.
__global__ __launch_bounds__(256) void k_snake(const float* __restrict__ pred,
                        const float* __restrict__ init,
                        float4* __restrict__ pA, float4* __restrict__ pB) {
    __shared__ float2 stxy[NN];
    __shared__ float swf[NN];
    __shared__ float sg[17], sdg[17];
    __shared__ float ssum;
    const int b = blockIdx.x;
    const int tid = threadIdx.x;
    const int i = tid >> 2;
    const int q = tid & 3;
    const float* p = pred + (size_t)b*HW;

    // ---- DoG taps (match reference exactly) ----
    if (tid < 17) {
        float xv = (float)(tid - 8);
        float e  = expf(-0.5f * (xv*0.5f)*(xv*0.5f));
        sg[tid]  = e;
        sdg[tid] = -(xv*0.25f) * e;
    }
    __syncthreads();
    if (tid == 0) {
        float s = 0.f;
        for (int k = 0; k < 17; ++k) s += sg[k];
        ssum = s;
    }
    __syncthreads();
    if (tid < 17) sg[tid] /= ssum;
    __syncthreads();

    float ar[16];
#pragma unroll
    for (int k = 0; k < 16; ++k) ar[k] = g_Ainv.a[i][q*16 + k];

    float px = init[(b*NN + i)*2 + 0];
    float py = init[(b*NN + i)*2 + 1];

    for (int s = 0; s < 20; ++s) {
        float x = fminf(fmaxf(px, 0.f), (float)(Hh-1));
        float y = fminf(fmaxf(py, 0.f), (float)(Ww-1));
        int x0i = (int)floorf(x); x0i = min(max(x0i, 0), Hh-2);
        int y0i = (int)floorf(y); y0i = min(max(y0i, 0), Ww-2);
        float fx = x - (float)x0i, fy = y - (float)y0i;

        // per-thread 18-tap column weights (registers via full unroll)
        float Wyg[18], Wyd[18];
#pragma unroll
        for (int t = 0; t < 18; ++t) {
            float a0 = (t < 17) ? sg[t]  : 0.f;
            float a1 = (t >= 1) ? sg[t-1]  : 0.f;
            float d0 = (t < 17) ? sdg[t] : 0.f;
            float d1 = (t >= 1) ? sdg[t-1] : 0.f;
            Wyg[t] = (1.f-fy)*a0 + fy*a1;
            Wyd[t] = (1.f-fy)*d0 + fy*d1;
        }
        const int ybase = y0i - 8;
        const bool fastcol = (ybase >= 0) && (y0i + 9 < Ww);

        float f0 = 0.f, f1 = 0.f;     // ch0: dg-x,g-y ; ch1: g-x,dg-y
#pragma unroll
        for (int k = 0; k < 5; ++k) {
            int srow = q + 4*k;
            if (srow < 18) {
                int xr = x0i + srow - 8;
                float rs_g = 0.f, rs_d = 0.f;
                if (xr >= 0 && xr < Hh) {
                    const float* rowp = p + xr*Ww + ybase;
                    if (fastcol) {
#pragma unroll
                        for (int t = 0; t < 18; ++t) {
                            float v = rowp[t];
                            rs_g = fmaf(Wyg[t], v, rs_g);
                            rs_d = fmaf(Wyd[t], v, rs_d);
                        }
                    } else {
#pragma unroll
                        for (int t = 0; t < 18; ++t) {
                            int yc = ybase + t;
                            float v = (yc >= 0 && yc < Ww) ? p[xr*Ww + yc] : 0.f;
                            rs_g = fmaf(Wyg[t], v, rs_g);
                            rs_d = fmaf(Wyd[t], v, rs_d);
                        }
                    }
                }
                float xg0 = (srow < 17) ? sg[srow]  : 0.f;
                float xg1 = (srow >= 1) ? sg[srow-1]  : 0.f;
                float xd0 = (srow < 17) ? sdg[srow] : 0.f;
                float xd1 = (srow >= 1) ? sdg[srow-1] : 0.f;
                float wxg = (1.f-fx)*xg0 + fx*xg1;
                float wxd = (1.f-fx)*xd0 + fx*xd1;
                f0 = fmaf(wxd, rs_g, f0);
                f1 = fmaf(wxg, rs_d, f1);
            }
        }
        // combine the 4 per-node partial sums (lanes i*4+q contiguous)
        f0 += __shfl_xor(f0, 1); f1 += __shfl_xor(f1, 1);
        f0 += __shfl_xor(f0, 2); f1 += __shfl_xor(f1, 2);
        float tx = px + 0.1f*(f0*10.f);   // EXTGRADFAC
        float ty = py + 0.1f*(f1*10.f);
        if (q == 0) stxy[i] = make_float2(tx, ty);
        __syncthreads();
        float ax = 0.f, ay = 0.f;
#pragma unroll
        for (int k = 0; k < 16; ++k) {
            float2 tv = stxy[q*16 + k];
            ax = fmaf(ar[k], tv.x, ax);
            ay = fmaf(ar[k], tv.y, ay);
        }
        ax += __shfl_xor(ax, 1); ay += __shfl_xor(ay, 1);
        ax += __shfl_xor(ax, 2); ay += __shfl_xor(ay, 2);
        px = ax; py = ay;
        __syncthreads();
    }
    if (q == 0) stxy[i] = make_float2(px, py);
    __syncthreads();

    // ---- radial widths: node-batched radius-1 probe + rare serial tail ----
    const int wid  = tid >> 6;
    const int lane = tid & 63;
    const bool active = lane < 36;
    const float theta = (float)(10*lane) * 0.017453292519943295f;
    const float cth = cosf(theta), sth = sinf(theta);

    float v1[16];
    unsigned inbm = 0u;
#pragma unroll
    for (int nc = 0; nc < 16; ++nc) {
        const int node = wid*16 + nc;
        const float sx = rintf(stxy[node].x);
        const float sy = rintf(stxy[node].y);
        int xi = (int)floorf(sx + cth);     // r = 1
        int yi = (int)floorf(sy + sth);
        bool inb = (xi >= 0) & (xi < Hh) & (yi >= 0) & (yi < Ww);
        inbm |= (inb ? 1u : 0u) << nc;
        int cx = min(max(xi, 0), Hh-1);
        int cy = min(max(yi, 0), Ww-1);
        v1[nc] = p[cx*Ww + cy];             // 16 independent loads in flight
    }
#pragma unroll
    for (int nc = 0; nc < 16; ++nc) {
        const int node = wid*16 + nc;
        bool inb = (inbm >> nc) & 1u;
        bool hit = active && inb && (v1[nc] > 0.f);   // sigmoid(-p)<0.5 <=> p>0
        bool oob = active && !inb;
        unsigned long long mh = __ballot(hit);
        unsigned long long mo = __ballot(oob);
        float w = 0.f;                       // r=1 resolution always => 0
        if (!(mh | mo)) {                    // wave-uniform rare path
            const float sx = rintf(stxy[node].x);
            const float sy = rintf(stxy[node].y);
            for (int r = 2; r < Hh; ++r) {
                float rf = (float)r;
                bool hit2 = false, oob2 = false;
                if (active) {
                    int xi = (int)floorf(sx + rf*cth);
                    int yi = (int)floorf(sy + rf*sth);
                    bool inb2 = (xi >= 0) & (xi < Hh) & (yi >= 0) & (yi < Ww);
                    if (!inb2) oob2 = true;
                    else if (p[xi*Ww + yi] > 0.f) hit2 = true;
                }
                unsigned long long mh2 = __ballot(hit2);
                unsigned long long mo2 = __ballot(oob2);
                if (mh2 | mo2) { w = mh2 ? (rf - 1.f) : 0.f; break; }
            }
        }
        if (lane == 0) swf[node] = w;
    }
    __syncthreads();

    // ---- segment prep ----
    if (tid < NSEG) {
        float2 P0 = stxy[tid], P1 = stxy[tid+1];
        float vx = P1.x - P0.x, vy = P1.y - P0.y;
        float vv = vx*vx + vy*vy + 1e-8f;
        float w0 = swf[tid], w1 = swf[tid+1];
        pA[b*NSEG + tid] = make_float4(P0.x, P0.y, vx, vy);
        pB[b*NSEG + tid] = make_float4(1.0f/vv, w0, w1 - w0, 0.f);
    }
}

// ------- render: 16x16 tiles, LDS-staged params, per-tile segment culling --
__global__ __launch_bounds__(256) void k_render(const float* __restrict__ pred,
                        const float4* __restrict__ pAg, const float4* __restrict__ pBg,
                        float* __restrict__ partial) {
    __shared__ float4 sSa[NSEG], sSb[NSEG];
    __shared__ int slist[NSEG];
    __shared__ int scount;
    __shared__ float red[256];
    const int b   = blockIdx.z;
    const int tid = threadIdx.x;
    const int row0 = blockIdx.x * 16, col0 = blockIdx.y * 16;
    if (tid == 0) scount = 0;
    if (tid < NSEG) {
        sSa[tid] = pAg[b*NSEG + tid];
        sSb[tid] = pBg[b*NSEG + tid];
    }
    __syncthreads();
    if (tid < NSEG) {
        const float4 A = sSa[tid];
        const float4 Bv = sSb[tid];
        float cx = (float)row0 + 7.5f, cy = (float)col0 + 7.5f;
        float dx = cx - A.x, dy = cy - A.y;
        float t = fmaf(dy, A.w, dx*A.z) * Bv.x;
        t = fminf(fmaxf(t, 0.f), 1.f);
        float ex = fmaf(-t, A.z, dx);
        float ey = fmaf(-t, A.w, dy);
        float dc = sqrtf(ex*ex + ey*ey);
        float wmax = fmaxf(Bv.y, Bv.y + Bv.z);
        float lim = fmaxf(15.0f, wmax) + 10.6066f + 0.05f;
        if (dc <= lim) {
            int idx = atomicAdd(&scount, 1);
            slist[idx] = tid;
        }
    }
    __syncthreads();
    const int cnt = scount;
    const int r = tid >> 4, c = tid & 15;
    const float fx = (float)(row0 + r), fy = (float)(col0 + c);
    float m1 = 1e30f, m2 = 1e30f;
    for (int k = 0; k < cnt; ++k) {
        const int s2 = slist[k];
        const float4 A = sSa[s2];
        const float4 Bv = sSb[s2];
        float dx = fx - A.x, dy = fy - A.y;
        float t = fmaf(dy, A.w, dx*A.z) * Bv.x;
        t = fminf(fmaxf(t, 0.f), 1.f);
        float ex = fmaf(-t, A.z, dx);
        float ey = fmaf(-t, A.w, dy);
        float d2 = fmaf(ex, ex, fmaf(ey, ey, 1e-12f));
        float wt = fmaf(t, Bv.z, Bv.y);
        m1 = fminf(m1, d2);
        m2 = fminf(m2, fmaf(-wt, wt, d2));
    }
    float dmap = fminf(sqrtf(m1), 15.f);
    float pm = (m2 <= 0.f) ? 1.f : 0.f;
    float pv = pred[(size_t)b*HW + (row0 + r)*Ww + (col0 + c)];
    float sg = 1.f/(1.f + expf(-pv));
    float t1 = pv - dmap, t2 = sg - pm;
    red[tid] = t1*t1 + t2*t2;
    __syncthreads();
    for (int off = 128; off > 0; off >>= 1) {
        if (tid < off) red[tid] += red[tid+off];
        __syncthreads();
    }
    if (tid == 0)
        partial[b*NTILES + blockIdx.y*TPB + blockIdx.x] = red[0];
}

__global__ void k_final(const float* __restrict__ partial, float* __restrict__ out, int n) {
    __shared__ double red[256];
    const int tid = threadIdx.x;
    double a = 0.0;
    for (int i = tid; i < n; i += 256) a += (double)partial[i];
    red[tid] = a; __syncthreads();
    for (int off = 128; off > 0; off >>= 1) {
        if (tid < off) red[tid] += red[tid+off];
        __syncthreads();
    }
    if (tid == 0) out[0] = (float)(red[0] / (double)((size_t)Bb*HW));
}

extern "C" void kernel_launch(void* const* d_in, const int* in_sizes, int n_in,
                              void* d_out, int out_size, void* d_ws, size_t ws_size,
                              hipStream_t stream) {
    const float* pred = (const float*)d_in[0];   // [4,1,384,384] f32
    const float* init = (const float*)d_in[1];   // [4,64,2] f32
    float* out = (float*)d_out;
    char* ws = (char*)d_ws;
    // ws: pA @0 | pB @4096 | partial @19456 (2304 f32)
    float4* pA     = (float4*)(ws);
    float4* pB     = (float4*)(ws + 4096);
    float* partial = (float*)(ws + 19456);

    k_snake <<<dim3(4),           dim3(256), 0, stream>>>(pred, init, pA, pB);
    k_render<<<dim3(TPB,TPB,Bb),  dim3(256), 0, stream>>>(pred, pA, pB, partial);
    k_final <<<dim3(1),           dim3(256), 0, stream>>>(partial, out, Bb*NTILES);
}

// Round 13
// 63.118 us; speedup vs baseline: 1.3784x; 1.3784x over previous
//
#include <hip/hip_runtime.h>

#define Hh 384
#define Ww 384
#define Bb 4
#define NN 64
#define HW (Hh*Ww)
#define NSEG (NN-1)
#define TPB 24                        // 24x24 tiles of 16x16
#define NTILES (TPB*TPB)              // 576 per batch

// ---------------- compile-time Ainv = (I + 0.1*A)^-1 (banded LU, f32) ------
struct AinvT { float a[NN][NN]; };
constexpr AinvT make_ainv() {
    AinvT R{};
    float d[NN] = {}, u1[NN] = {}, u2[NN] = {}, b1[NN] = {}, L1[NN] = {}, L2[NN] = {};
    for (int k = 0; k < NN-1; ++k) { d[k] += 0.01f; d[k+1] += 0.01f; u1[k] -= 0.01f; }
    for (int k = 0; k < NN-2; ++k) {
        d[k] += 0.01f; d[k+1] += 0.04f; d[k+2] += 0.01f;
        u1[k] -= 0.02f; u1[k+1] -= 0.02f; u2[k] += 0.01f;
    }
    for (int k = 0; k < NN; ++k) {
        d[k]  = 1.0f + 0.1f*d[k];
        u1[k] = 0.1f*u1[k];
        u2[k] = 0.1f*u2[k];
        b1[k] = u1[k];
    }
    for (int k = 0; k < NN; ++k) {
        float di = d[k];
        if (k+1 < NN) { float l = b1[k]/di; L1[k] = l; d[k+1] -= l*u1[k]; if (k+2 < NN) u1[k+1] -= l*u2[k]; }
        if (k+2 < NN) { float l = u2[k]/di; L2[k] = l; b1[k+1] -= l*u1[k]; d[k+2] -= l*u2[k]; }
    }
    for (int t = 0; t < NN; ++t) {
        float y[NN] = {}, x[NN] = {};
        for (int k = 0; k < NN; ++k) {
            float v = (k == t) ? 1.0f : 0.0f;
            if (k >= 1) v -= L1[k-1]*y[k-1];
            if (k >= 2) v -= L2[k-2]*y[k-2];
            y[k] = v;
        }
        for (int kk = 0; kk < NN; ++kk) {
            int k = NN-1-kk;
            float v = y[k];
            if (k+1 < NN) v -= u1[k]*x[k+1];
            if (k+2 < NN) v -= u2[k]*x[k+2];
            x[k] = v/d[k];
        }
        for (int k = 0; k < NN; ++k) R.a[k][t] = x[k];
    }
    return R;
}
__device__ constexpr AinvT g_Ainv = make_ainv();

// ---------------- conv (separable DoG) -> gimg [B][H][W][2] ----------------
#define TILE 32
#define HALO 8
__global__ __launch_bounds__(256) void k_conv(const float* __restrict__ img,
        float2* __restrict__ gimg) {
    __shared__ float sIn[TILE+2*HALO][TILE+2*HALO];      // 48x48
    __shared__ float sColG[TILE+2*HALO][TILE];
    __shared__ float sColD[TILE+2*HALO][TILE];
    __shared__ float gtap[17], dtap[17];
    const int b  = blockIdx.z;
    const int x0 = blockIdx.x * TILE;
    const int y0 = blockIdx.y * TILE;
    const int tid = threadIdx.x;
    if (tid == 0) {
        float s = 0.f;
        for (int i = 0; i < 17; ++i) {
            float xv = (float)(i - 8);
            float e  = expf(-0.5f * (xv*0.5f)*(xv*0.5f));
            gtap[i] = e; s += e;
            dtap[i] = -(xv*0.25f) * e;
        }
        for (int i = 0; i < 17; ++i) gtap[i] /= s;
    }
    const float* im = img + b*HW;
    for (int idx = tid; idx < 48*48; idx += blockDim.x) {
        int r = idx / 48, c = idx % 48;
        int gx = x0 + r - HALO, gy = y0 + c - HALO;
        float v = 0.f;
        if (gx >= 0 && gx < Hh && gy >= 0 && gy < Ww) v = im[gx*Ww + gy];
        sIn[r][c] = v;
    }
    __syncthreads();
    for (int idx = tid; idx < 48*TILE; idx += blockDim.x) {
        int r = idx / TILE, c = idx % TILE;
        float ag = 0.f, ad = 0.f;
#pragma unroll
        for (int k = 0; k < 17; ++k) {
            float v = sIn[r][c+k];
            ag += gtap[k]*v;
            ad += dtap[k]*v;
        }
        sColG[r][c] = ag; sColD[r][c] = ad;
    }
    __syncthreads();
    float2* gg = gimg + (size_t)b*HW;
    for (int idx = tid; idx < TILE*TILE; idx += blockDim.x) {
        int xo = idx / TILE, c = idx % TILE;
        float a0 = 0.f, a1 = 0.f;
#pragma unroll
        for (int k = 0; k < 17; ++k) {
            a0 += dtap[k]*sColG[xo+k][c];
            a1 += gtap[k]*sColD[xo+k][c];
        }
        int gx = x0+xo, gy = y0+c;
        gg[gx*Ww+gy] = make_float2(10.f*a0, 10.f*a1);
    }
}

// ------- snake (20 steps, const Ainv) + node-batched widths + prep ---------
__global__ __launch_bounds__(256) void k_snake(const float2* __restrict__ gimg,
                        const float* __restrict__ pred, const float* __restrict__ init,
                        float4* __restrict__ pA, float4* __restrict__ pB,
                        float* __restrict__ out) {
    __shared__ float2 stxy[NN];
    __shared__ float swf[NN];
    const int b = blockIdx.x;
    const int tid = threadIdx.x;
    const int i = tid >> 2;
    const int q = tid & 3;

    if (b == 0 && tid == 0) out[0] = 0.f;   // zero accumulator each call

    float ar[16];
#pragma unroll
    for (int k = 0; k < 16; ++k) ar[k] = g_Ainv.a[i][q*16 + k];

    float px = init[(b*NN + i)*2 + 0];
    float py = init[(b*NN + i)*2 + 1];
    const float2* g = gimg + (size_t)b*HW;

    for (int s = 0; s < 20; ++s) {
        float x = fminf(fmaxf(px, 0.f), (float)(Hh-1));
        float y = fminf(fmaxf(py, 0.f), (float)(Ww-1));
        int x0i = (int)floorf(x); x0i = min(max(x0i, 0), Hh-2);
        int y0i = (int)floorf(y); y0i = min(max(y0i, 0), Ww-2);
        float fx = x - (float)x0i, fy = y - (float)y0i;
        int base = x0i*Ww + y0i;
        if (q == 0) {
            float2 v00 = g[base],    v01 = g[base+1];
            float2 v10 = g[base+Ww], v11 = g[base+Ww+1];
            float t0x = v00.x*(1.f-fy) + v01.x*fy;
            float t0y = v00.y*(1.f-fy) + v01.y*fy;
            float b0x = v10.x*(1.f-fy) + v11.x*fy;
            float b0y = v10.y*(1.f-fy) + v11.y*fy;
            float f0 = t0x*(1.f-fx) + b0x*fx;
            float f1 = t0y*(1.f-fx) + b0y*fx;
            stxy[i] = make_float2(px + 0.1f*f0, py + 0.1f*f1);
        }
        __syncthreads();
        float ax = 0.f, ay = 0.f;
#pragma unroll
        for (int k = 0; k < 16; ++k) {
            float2 tv = stxy[q*16 + k];
            ax = fmaf(ar[k], tv.x, ax);
            ay = fmaf(ar[k], tv.y, ay);
        }
        ax += __shfl_xor(ax, 1); ay += __shfl_xor(ay, 1);
        ax += __shfl_xor(ax, 2); ay += __shfl_xor(ay, 2);
        px = ax; py = ay;
        __syncthreads();
    }
    if (q == 0) stxy[i] = make_float2(px, py);
    __syncthreads();

    // ---- radial widths: node-batched radius-1 probe + rare serial tail ----
    const float* p = pred + (size_t)b*HW;
    const int wid  = tid >> 6;
    const int lane = tid & 63;
    const bool active = lane < 36;
    const float theta = (float)(10*lane) * 0.017453292519943295f;
    const float cth = cosf(theta), sth = sinf(theta);

    float v1[16];
    unsigned inbm = 0u;
#pragma unroll
    for (int nc = 0; nc < 16; ++nc) {
        const int node = wid*16 + nc;
        const float sx = rintf(stxy[node].x);
        const float sy = rintf(stxy[node].y);
        int xi = (int)floorf(sx + cth);     // r = 1
        int yi = (int)floorf(sy + sth);
        bool inb = (xi >= 0) & (xi < Hh) & (yi >= 0) & (yi < Ww);
        inbm |= (inb ? 1u : 0u) << nc;
        int cx = min(max(xi, 0), Hh-1);
        int cy = min(max(yi, 0), Ww-1);
        v1[nc] = p[cx*Ww + cy];             // 16 independent loads in flight
    }
#pragma unroll
    for (int nc = 0; nc < 16; ++nc) {
        const int node = wid*16 + nc;
        bool inb = (inbm >> nc) & 1u;
        bool hit = active && inb && (v1[nc] > 0.f);   // sigmoid(-p)<0.5 <=> p>0
        bool oob = active && !inb;
        unsigned long long mh = __ballot(hit);
        unsigned long long mo = __ballot(oob);
        float w = 0.f;                       // r=1 resolution always => 0
        if (!(mh | mo)) {                    // wave-uniform rare path
            const float sx = rintf(stxy[node].x);
            const float sy = rintf(stxy[node].y);
            for (int r = 2; r < Hh; ++r) {
                float rf = (float)r;
                bool hit2 = false, oob2 = false;
                if (active) {
                    int xi = (int)floorf(sx + rf*cth);
                    int yi = (int)floorf(sy + rf*sth);
                    bool inb2 = (xi >= 0) & (xi < Hh) & (yi >= 0) & (yi < Ww);
                    if (!inb2) oob2 = true;
                    else if (p[xi*Ww + yi] > 0.f) hit2 = true;
                }
                unsigned long long mh2 = __ballot(hit2);
                unsigned long long mo2 = __ballot(oob2);
                if (mh2 | mo2) { w = mh2 ? (rf - 1.f) : 0.f; break; }
            }
        }
        if (lane == 0) swf[node] = w;
    }
    __syncthreads();

    // ---- segment prep ----
    if (tid < NSEG) {
        float2 P0 = stxy[tid], P1 = stxy[tid+1];
        float vx = P1.x - P0.x, vy = P1.y - P0.y;
        float vv = vx*vx + vy*vy + 1e-8f;
        float w0 = swf[tid], w1 = swf[tid+1];
        pA[b*NSEG + tid] = make_float4(P0.x, P0.y, vx, vy);
        pB[b*NSEG + tid] = make_float4(1.0f/vv, w0, w1 - w0, 0.f);
    }
}

// ------- render: 16x16 tiles, cull, fused loss; plain atomic accumulate ----
__global__ __launch_bounds__(256) void k_render(const float* __restrict__ pred,
                        const float4* __restrict__ pAg, const float4* __restrict__ pBg,
                        float* __restrict__ out) {
    __shared__ float4 sSa[NSEG], sSb[NSEG];
    __shared__ int slist[NSEG];
    __shared__ int scount;
    __shared__ float red[256];
    const int b   = blockIdx.z;
    const int tid = threadIdx.x;
    const int row0 = blockIdx.x * 16, col0 = blockIdx.y * 16;
    if (tid == 0) scount = 0;
    if (tid < NSEG) {
        sSa[tid] = pAg[b*NSEG + tid];
        sSb[tid] = pBg[b*NSEG + tid];
    }
    __syncthreads();
    if (tid < NSEG) {
        const float4 A = sSa[tid];
        const float4 Bv = sSb[tid];
        float cx = (float)row0 + 7.5f, cy = (float)col0 + 7.5f;
        float dx = cx - A.x, dy = cy - A.y;
        float t = fmaf(dy, A.w, dx*A.z) * Bv.x;
        t = fminf(fmaxf(t, 0.f), 1.f);
        float ex = fmaf(-t, A.z, dx);
        float ey = fmaf(-t, A.w, dy);
        float dc = sqrtf(ex*ex + ey*ey);
        float wmax = fmaxf(Bv.y, Bv.y + Bv.z);
        float lim = fmaxf(15.0f, wmax) + 10.6066f + 0.05f;
        if (dc <= lim) {
            int idx = atomicAdd(&scount, 1);
            slist[idx] = tid;
        }
    }
    __syncthreads();
    const int cnt = scount;
    const int r = tid >> 4, c = tid & 15;
    const float fx = (float)(row0 + r), fy = (float)(col0 + c);
    float m1 = 1e30f, m2 = 1e30f;
    for (int k = 0; k < cnt; ++k) {
        const int s2 = slist[k];
        const float4 A = sSa[s2];
        const float4 Bv = sSb[s2];
        float dx = fx - A.x, dy = fy - A.y;
        float t = fmaf(dy, A.w, dx*A.z) * Bv.x;
        t = fminf(fmaxf(t, 0.f), 1.f);
        float ex = fmaf(-t, A.z, dx);
        float ey = fmaf(-t, A.w, dy);
        float d2 = fmaf(ex, ex, fmaf(ey, ey, 1e-12f));
        float wt = fmaf(t, Bv.z, Bv.y);
        m1 = fminf(m1, d2);
        m2 = fminf(m2, fmaf(-wt, wt, d2));
    }
    float dmap = fminf(sqrtf(m1), 15.f);
    float pm = (m2 <= 0.f) ? 1.f : 0.f;
    float pv = pred[(size_t)b*HW + (row0 + r)*Ww + (col0 + c)];
    float sg = 1.f/(1.f + expf(-pv));
    float t1 = pv - dmap, t2 = sg - pm;
    red[tid] = t1*t1 + t2*t2;
    __syncthreads();
    for (int off = 128; off > 0; off >>= 1) {
        if (tid < off) red[tid] += red[tid+off];
        __syncthreads();
    }
    if (tid == 0)
        atomicAdd(out, red[0] * (1.0f/((float)Bb*(float)HW)));  // fire-and-forget
}

extern "C" void kernel_launch(void* const* d_in, const int* in_sizes, int n_in,
                              void* d_out, int out_size, void* d_ws, size_t ws_size,
                              hipStream_t stream) {
    const float* pred = (const float*)d_in[0];   // [4,1,384,384] f32
    const float* init = (const float*)d_in[1];   // [4,64,2] f32
    float* out = (float*)d_out;
    char* ws = (char*)d_ws;
    // ws: pA @0 | pB @4096 | gimg @28672
    float4* pA     = (float4*)(ws);
    float4* pB     = (float4*)(ws + 4096);
    float2* gimg   = (float2*)(ws + 28672);

    k_conv  <<<dim3(12,12,4),     dim3(256), 0, stream>>>(pred, gimg);
    k_snake <<<dim3(4),           dim3(256), 0, stream>>>(gimg, pred, init, pA, pB, out);
    k_render<<<dim3(TPB,TPB,Bb),  dim3(256), 0, stream>>>(pred, pA, pB, out);
}

// Round 14
// 39.955 us; speedup vs baseline: 2.1775x; 1.5797x over previous
//
#include <hip/hip_runtime.h>

#define Hh 384
#define Ww 384
#define Bb 4
#define NN 64
#define HW (Hh*Ww)
#define NSEG (NN-1)
#define TPB 24                        // 24x24 tiles of 16x16
#define NTILES (TPB*TPB)              // 576 per batch

// ---------------- compile-time Ainv = (I + 0.1*A)^-1 (banded LU, f32) ------
struct AinvT { float a[NN][NN]; };
constexpr AinvT make_ainv() {
    AinvT R{};
    float d[NN] = {}, u1[NN] = {}, u2[NN] = {}, b1[NN] = {}, L1[NN] = {}, L2[NN] = {};
    for (int k = 0; k < NN-1; ++k) { d[k] += 0.01f; d[k+1] += 0.01f; u1[k] -= 0.01f; }
    for (int k = 0; k < NN-2; ++k) {
        d[k] += 0.01f; d[k+1] += 0.04f; d[k+2] += 0.01f;
        u1[k] -= 0.02f; u1[k+1] -= 0.02f; u2[k] += 0.01f;
    }
    for (int k = 0; k < NN; ++k) {
        d[k]  = 1.0f + 0.1f*d[k];
        u1[k] = 0.1f*u1[k];
        u2[k] = 0.1f*u2[k];
        b1[k] = u1[k];
    }
    for (int k = 0; k < NN; ++k) {
        float di = d[k];
        if (k+1 < NN) { float l = b1[k]/di; L1[k] = l; d[k+1] -= l*u1[k]; if (k+2 < NN) u1[k+1] -= l*u2[k]; }
        if (k+2 < NN) { float l = u2[k]/di; L2[k] = l; b1[k+1] -= l*u1[k]; d[k+2] -= l*u2[k]; }
    }
    for (int t = 0; t < NN; ++t) {
        float y[NN] = {}, x[NN] = {};
        for (int k = 0; k < NN; ++k) {
            float v = (k == t) ? 1.0f : 0.0f;
            if (k >= 1) v -= L1[k-1]*y[k-1];
            if (k >= 2) v -= L2[k-2]*y[k-2];
            y[k] = v;
        }
        for (int kk = 0; kk < NN; ++kk) {
            int k = NN-1-kk;
            float v = y[k];
            if (k+1 < NN) v -= u1[k]*x[k+1];
            if (k+2 < NN) v -= u2[k]*x[k+2];
            x[k] = v/d[k];
        }
        for (int k = 0; k < NN; ++k) R.a[k][t] = x[k];
    }
    return R;
}
__device__ constexpr AinvT g_Ainv = make_ainv();

// ---------------- conv (separable DoG) -> gimg [B][H][W][2] ----------------
#define TILE 32
#define HALO 8
__global__ __launch_bounds__(256) void k_conv(const float* __restrict__ img,
        float2* __restrict__ gimg) {
    __shared__ float sIn[TILE+2*HALO][TILE+2*HALO];      // 48x48
    __shared__ float sColG[TILE+2*HALO][TILE];
    __shared__ float sColD[TILE+2*HALO][TILE];
    __shared__ float gtap[17], dtap[17];
    const int b  = blockIdx.z;
    const int x0 = blockIdx.x * TILE;
    const int y0 = blockIdx.y * TILE;
    const int tid = threadIdx.x;
    if (tid == 0) {
        float s = 0.f;
        for (int i = 0; i < 17; ++i) {
            float xv = (float)(i - 8);
            float e  = expf(-0.5f * (xv*0.5f)*(xv*0.5f));
            gtap[i] = e; s += e;
            dtap[i] = -(xv*0.25f) * e;
        }
        for (int i = 0; i < 17; ++i) gtap[i] /= s;
    }
    const float* im = img + b*HW;
    for (int idx = tid; idx < 48*48; idx += blockDim.x) {
        int r = idx / 48, c = idx % 48;
        int gx = x0 + r - HALO, gy = y0 + c - HALO;
        float v = 0.f;
        if (gx >= 0 && gx < Hh && gy >= 0 && gy < Ww) v = im[gx*Ww + gy];
        sIn[r][c] = v;
    }
    __syncthreads();
    for (int idx = tid; idx < 48*TILE; idx += blockDim.x) {
        int r = idx / TILE, c = idx % TILE;
        float ag = 0.f, ad = 0.f;
#pragma unroll
        for (int k = 0; k < 17; ++k) {
            float v = sIn[r][c+k];
            ag += gtap[k]*v;
            ad += dtap[k]*v;
        }
        sColG[r][c] = ag; sColD[r][c] = ad;
    }
    __syncthreads();
    float2* gg = gimg + (size_t)b*HW;
    for (int idx = tid; idx < TILE*TILE; idx += blockDim.x) {
        int xo = idx / TILE, c = idx % TILE;
        float a0 = 0.f, a1 = 0.f;
#pragma unroll
        for (int k = 0; k < 17; ++k) {
            a0 += dtap[k]*sColG[xo+k][c];
            a1 += gtap[k]*sColD[xo+k][c];
        }
        int gx = x0+xo, gy = y0+c;
        gg[gx*Ww+gy] = make_float2(10.f*a0, 10.f*a1);
    }
}

// ------- snake (20 steps, const Ainv) + node-batched widths + prep ---------
__global__ __launch_bounds__(256) void k_snake(const float2* __restrict__ gimg,
                        const float* __restrict__ pred, const float* __restrict__ init,
                        float4* __restrict__ pA, float4* __restrict__ pB) {
    __shared__ float2 stxy[NN];
    __shared__ float swf[NN];
    const int b = blockIdx.x;
    const int tid = threadIdx.x;
    const int i = tid >> 2;
    const int q = tid & 3;

    float ar[16];
#pragma unroll
    for (int k = 0; k < 16; ++k) ar[k] = g_Ainv.a[i][q*16 + k];

    float px = init[(b*NN + i)*2 + 0];
    float py = init[(b*NN + i)*2 + 1];
    const float2* g = gimg + (size_t)b*HW;

    for (int s = 0; s < 20; ++s) {
        float x = fminf(fmaxf(px, 0.f), (float)(Hh-1));
        float y = fminf(fmaxf(py, 0.f), (float)(Ww-1));
        int x0i = (int)floorf(x); x0i = min(max(x0i, 0), Hh-2);
        int y0i = (int)floorf(y); y0i = min(max(y0i, 0), Ww-2);
        float fx = x - (float)x0i, fy = y - (float)y0i;
        int base = x0i*Ww + y0i;
        if (q == 0) {
            float2 v00 = g[base],    v01 = g[base+1];
            float2 v10 = g[base+Ww], v11 = g[base+Ww+1];
            float t0x = v00.x*(1.f-fy) + v01.x*fy;
            float t0y = v00.y*(1.f-fy) + v01.y*fy;
            float b0x = v10.x*(1.f-fy) + v11.x*fy;
            float b0y = v10.y*(1.f-fy) + v11.y*fy;
            float f0 = t0x*(1.f-fx) + b0x*fx;
            float f1 = t0y*(1.f-fx) + b0y*fx;
            stxy[i] = make_float2(px + 0.1f*f0, py + 0.1f*f1);
        }
        __syncthreads();
        float ax = 0.f, ay = 0.f;
#pragma unroll
        for (int k = 0; k < 16; ++k) {
            float2 tv = stxy[q*16 + k];
            ax = fmaf(ar[k], tv.x, ax);
            ay = fmaf(ar[k], tv.y, ay);
        }
        ax += __shfl_xor(ax, 1); ay += __shfl_xor(ay, 1);
        ax += __shfl_xor(ax, 2); ay += __shfl_xor(ay, 2);
        px = ax; py = ay;
        __syncthreads();
    }
    if (q == 0) stxy[i] = make_float2(px, py);
    __syncthreads();

    // ---- radial widths: node-batched radius-1 probe + rare serial tail ----
    const float* p = pred + (size_t)b*HW;
    const int wid  = tid >> 6;
    const int lane = tid & 63;
    const bool active = lane < 36;
    const float theta = (float)(10*lane) * 0.017453292519943295f;
    const float cth = cosf(theta), sth = sinf(theta);

    float v1[16];
    unsigned inbm = 0u;
#pragma unroll
    for (int nc = 0; nc < 16; ++nc) {
        const int node = wid*16 + nc;
        const float sx = rintf(stxy[node].x);
        const float sy = rintf(stxy[node].y);
        int xi = (int)floorf(sx + cth);     // r = 1
        int yi = (int)floorf(sy + sth);
        bool inb = (xi >= 0) & (xi < Hh) & (yi >= 0) & (yi < Ww);
        inbm |= (inb ? 1u : 0u) << nc;
        int cx = min(max(xi, 0), Hh-1);
        int cy = min(max(yi, 0), Ww-1);
        v1[nc] = p[cx*Ww + cy];             // 16 independent loads in flight
    }
#pragma unroll
    for (int nc = 0; nc < 16; ++nc) {
        const int node = wid*16 + nc;
        bool inb = (inbm >> nc) & 1u;
        bool hit = active && inb && (v1[nc] > 0.f);   // sigmoid(-p)<0.5 <=> p>0
        bool oob = active && !inb;
        unsigned long long mh = __ballot(hit);
        unsigned long long mo = __ballot(oob);
        float w = 0.f;                       // r=1 resolution always => 0
        if (!(mh | mo)) {                    // wave-uniform rare path
            const float sx = rintf(stxy[node].x);
            const float sy = rintf(stxy[node].y);
            for (int r = 2; r < Hh; ++r) {
                float rf = (float)r;
                bool hit2 = false, oob2 = false;
                if (active) {
                    int xi = (int)floorf(sx + rf*cth);
                    int yi = (int)floorf(sy + rf*sth);
                    bool inb2 = (xi >= 0) & (xi < Hh) & (yi >= 0) & (yi < Ww);
                    if (!inb2) oob2 = true;
                    else if (p[xi*Ww + yi] > 0.f) hit2 = true;
                }
                unsigned long long mh2 = __ballot(hit2);
                unsigned long long mo2 = __ballot(oob2);
                if (mh2 | mo2) { w = mh2 ? (rf - 1.f) : 0.f; break; }
            }
        }
        if (lane == 0) swf[node] = w;
    }
    __syncthreads();

    // ---- segment prep ----
    if (tid < NSEG) {
        float2 P0 = stxy[tid], P1 = stxy[tid+1];
        float vx = P1.x - P0.x, vy = P1.y - P0.y;
        float vv = vx*vx + vy*vy + 1e-8f;
        float w0 = swf[tid], w1 = swf[tid+1];
        pA[b*NSEG + tid] = make_float4(P0.x, P0.y, vx, vy);
        pB[b*NSEG + tid] = make_float4(1.0f/vv, w0, w1 - w0, 0.f);
    }
}

// ------- render: 16x16 tiles, LDS-staged params, per-tile segment culling --
__global__ __launch_bounds__(256) void k_render(const float* __restrict__ pred,
                        const float4* __restrict__ pAg, const float4* __restrict__ pBg,
                        float* __restrict__ partial) {
    __shared__ float4 sSa[NSEG], sSb[NSEG];
    __shared__ int slist[NSEG];
    __shared__ int scount;
    __shared__ float red[256];
    const int b   = blockIdx.z;
    const int tid = threadIdx.x;
    const int row0 = blockIdx.x * 16, col0 = blockIdx.y * 16;
    if (tid == 0) scount = 0;
    if (tid < NSEG) {
        sSa[tid] = pAg[b*NSEG + tid];
        sSb[tid] = pBg[b*NSEG + tid];
    }
    __syncthreads();
    if (tid < NSEG) {
        const float4 A = sSa[tid];
        const float4 Bv = sSb[tid];
        float cx = (float)row0 + 7.5f, cy = (float)col0 + 7.5f;
        float dx = cx - A.x, dy = cy - A.y;
        float t = fmaf(dy, A.w, dx*A.z) * Bv.x;
        t = fminf(fmaxf(t, 0.f), 1.f);
        float ex = fmaf(-t, A.z, dx);
        float ey = fmaf(-t, A.w, dy);
        float dc = sqrtf(ex*ex + ey*ey);
        float wmax = fmaxf(Bv.y, Bv.y + Bv.z);
        float lim = fmaxf(15.0f, wmax) + 10.6066f + 0.05f;
        if (dc <= lim) {
            int idx = atomicAdd(&scount, 1);
            slist[idx] = tid;
        }
    }
    __syncthreads();
    const int cnt = scount;
    const int r = tid >> 4, c = tid & 15;
    const float fx = (float)(row0 + r), fy = (float)(col0 + c);
    float m1 = 1e30f, m2 = 1e30f;
    for (int k = 0; k < cnt; ++k) {
        const int s2 = slist[k];
        const float4 A = sSa[s2];
        const float4 Bv = sSb[s2];
        float dx = fx - A.x, dy = fy - A.y;
        float t = fmaf(dy, A.w, dx*A.z) * Bv.x;
        t = fminf(fmaxf(t, 0.f), 1.f);
        float ex = fmaf(-t, A.z, dx);
        float ey = fmaf(-t, A.w, dy);
        float d2 = fmaf(ex, ex, fmaf(ey, ey, 1e-12f));
        float wt = fmaf(t, Bv.z, Bv.y);
        m1 = fminf(m1, d2);
        m2 = fminf(m2, fmaf(-wt, wt, d2));
    }
    float dmap = fminf(sqrtf(m1), 15.f);
    float pm = (m2 <= 0.f) ? 1.f : 0.f;
    float pv = pred[(size_t)b*HW + (row0 + r)*Ww + (col0 + c)];
    float sg = 1.f/(1.f + expf(-pv));
    float t1 = pv - dmap, t2 = sg - pm;
    red[tid] = t1*t1 + t2*t2;
    __syncthreads();
    for (int off = 128; off > 0; off >>= 1) {
        if (tid < off) red[tid] += red[tid+off];
        __syncthreads();
    }
    if (tid == 0)
        partial[b*NTILES + blockIdx.y*TPB + blockIdx.x] = red[0];
}

__global__ void k_final(const float* __restrict__ partial, float* __restrict__ out, int n) {
    __shared__ double red[256];
    const int tid = threadIdx.x;
    double a = 0.0;
    for (int i = tid; i < n; i += 256) a += (double)partial[i];
    red[tid] = a; __syncthreads();
    for (int off = 128; off > 0; off >>= 1) {
        if (tid < off) red[tid] += red[tid+off];
        __syncthreads();
    }
    if (tid == 0) out[0] = (float)(red[0] / (double)((size_t)Bb*HW));
}

extern "C" void kernel_launch(void* const* d_in, const int* in_sizes, int n_in,
                              void* d_out, int out_size, void* d_ws, size_t ws_size,
                              hipStream_t stream) {
    const float* pred = (const float*)d_in[0];   // [4,1,384,384] f32
    const float* init = (const float*)d_in[1];   // [4,64,2] f32
    float* out = (float*)d_out;
    char* ws = (char*)d_ws;
    // ws: pA @0 | pB @4096 | partial @19456 (2304 f32) | gimg @28672
    float4* pA     = (float4*)(ws);
    float4* pB     = (float4*)(ws + 4096);
    float* partial = (float*)(ws + 19456);
    float2* gimg   = (float2*)(ws + 28672);

    k_conv  <<<dim3(12,12,4),     dim3(256), 0, stream>>>(pred, gimg);
    k_snake <<<dim3(4),           dim3(256), 0, stream>>>(gimg, pred, init, pA, pB);
    k_render<<<dim3(TPB,TPB,Bb),  dim3(256), 0, stream>>>(pred, pA, pB, partial);
    k_final <<<dim3(1),           dim3(256), 0, stream>>>(partial, out, Bb*NTILES);
}